// Round 17
// baseline (83.404 us; speedup 1.0000x reference)
//
#include <hip/hip_runtime.h>

constexpr float EPS = 1e-5f;

typedef __attribute__((ext_vector_type(8))) short bf16x8;
typedef __attribute__((ext_vector_type(4))) float f32x4;

// d_ws layout (bytes):
//   0      : w3p[8nt][4ks][64][8]  bf16, BN-folded. ks 0,1 = h2 rows (k<64); ks 2,3 = agg rows (k>=64)
//   32768  : w2p[2sel][4nt][64][8] bf16, BN-folded. sel0 = w2 rows 0-15 (h1), sel1 = rows 16-31 (agg); k-slots>=16 ZERO
//   40960  : w1p[64][8]            bf16, BN-folded, zeros for k>=8
//   41984  : bb1 f32[16] ; 42048: bb2 f32[64] ; 42304: bb3 f32[128]
#define W2P_OFF 32768
#define W1P_OFF 40960
#define B1_OFF  41984
#define B2_OFF  42048
#define B3_OFF  42304

#define APAD 16   // sAfrag row stride in ushorts (16 ch, no pad)

__device__ __forceinline__ ushort f2bf(float x) {
    union { float f; unsigned u; } a; a.f = x;
    unsigned r = a.u + 0x7fffu + ((a.u >> 16) & 1u);   // RTNE (finite inputs only)
    return (ushort)(r >> 16);
}

__device__ __forceinline__ unsigned cvtpk(float lo, float hi) {
    unsigned r;
    asm("v_cvt_pk_bf16_f32 %0, %1, %2" : "=v"(r) : "v"(lo), "v"(hi));
    return r;
}

__global__ void vfe_prep(
    const float* __restrict__ w1, const float* __restrict__ b1,
    const float* __restrict__ g1, const float* __restrict__ be1,
    const float* __restrict__ m1, const float* __restrict__ v1,
    const float* __restrict__ w2, const float* __restrict__ b2,
    const float* __restrict__ g2, const float* __restrict__ be2,
    const float* __restrict__ m2, const float* __restrict__ v2,
    const float* __restrict__ w3, const float* __restrict__ b3,
    const float* __restrict__ g3, const float* __restrict__ be3,
    const float* __restrict__ m3, const float* __restrict__ v3,
    void* __restrict__ ws)
{
    ushort* w3p = (ushort*)ws;
    ushort* w2p = (ushort*)((char*)ws + W2P_OFF);
    ushort* w1p = (ushort*)((char*)ws + W1P_OFF);
    float*  bb1 = (float*)((char*)ws + B1_OFF);
    float*  bb2 = (float*)((char*)ws + B2_OFF);
    float*  bb3 = (float*)((char*)ws + B3_OFF);

    const int i = blockIdx.x * 256 + threadIdx.x;
    if (i < 16384) {                       // w3p: ((nt*4+ks)*64 + l)*8 + e
        const int e = i & 7, l = (i >> 3) & 63, rest = i >> 9;
        const int ks = rest & 3, nt = rest >> 2, g = l >> 4;
        const int k = ks * 32 + g * 8 + e;
        const int n = nt * 16 + (l & 15);
        const float s = g3[n] * rsqrtf(v3[n] + EPS);
        w3p[i] = f2bf(w3[k * 128 + n] * s);
    } else if (i < 20480) {                // w2p: ((sel*4+nt)*64 + l)*8 + e ; zeros k>=16
        const int j = i - 16384;
        const int e = j & 7, l = (j >> 3) & 63, rest = j >> 9;
        const int nt = rest & 3, sel = rest >> 2;
        const int klog = (l >> 4) * 8 + e;             // 0..31, real only <16
        const int n = nt * 16 + (l & 15);
        const float s = g2[n] * rsqrtf(v2[n] + EPS);
        w2p[j] = (klog < 16) ? f2bf(w2[(sel * 16 + klog) * 64 + n] * s) : (ushort)0;
    } else if (i < 20992) {                // w1p: l*8 + e, zeros for k>=8
        const int j = i - 20480;
        const int e = j & 7, l = j >> 3;
        const int klog = (l >> 4) * 8 + e;
        const int u = l & 15;
        const float s = g1[u] * rsqrtf(v1[u] + EPS);
        w1p[j] = (klog < 8) ? f2bf(w1[klog * 16 + u] * s) : (ushort)0;
    } else if (i < 21200) {
        const int j = i - 20992;
        if (j < 16) {
            const int u = j;
            bb1[u] = (b1[u] - m1[u]) * (g1[u] * rsqrtf(v1[u] + EPS)) + be1[u];
        } else if (j < 80) {
            const int u = j - 16;
            bb2[u] = (b2[u] - m2[u]) * (g2[u] * rsqrtf(v2[u] + EPS)) + be2[u];
        } else {
            const int u = j - 80;
            bb3[u] = (b3[u] - m3[u]) * (g3[u] * rsqrtf(v3[u] + EPS)) + be3[u];
        }
    }
}

#define NV(v)   ((v)==0?nv0:(v)==1?nv1:(v)==2?nv2:nv3)
#define LIM(v)  ((v)==0?lim0:(v)==1?lim1:(v)==2?lim2:lim3)
#define FULL(v) ((v)==0?full0:(v)==1?full1:(v)==2?full2:full3)

// 4 voxels per block, 256 threads / 4 waves. Tiles 3v..3v+2 = voxel v.
// R16 structure; R17 = sAfrag unioned into sBfrag (LDS 25.2 KB -> 6 blocks/CU),
// L2 split into compute-all -> barrier -> epilogue-all so the union is race-free.
__global__ __launch_bounds__(256, 6) void vfe_fused(
    const float* __restrict__ feat,
    const int* __restrict__ nvox,
    const void* __restrict__ ws,
    float* __restrict__ out,
    int K)
{
    __shared__ __align__(16) ushort sBfrag[12 * 2 * 64 * 8]; // h2, fragment order. 24,576 B
    __shared__ __align__(16) ushort sAgg1bf[4][16];          //                        128 B
    __shared__ __align__(16) ushort sAgg2bf[4][64];          //                        512 B

    // Unions into sBfrag (lifetimes audited):
    //   sX0bf : bytes 0..3,071  (written stage0, read L1; dead after L1)
    //   sAfrag: bytes 3,072..9,215 (written L1, read L2-compute; dead after barrier #2)
    // sBfrag h2 writes happen only in L2-epilogue, after barrier #2.
    ushort (*sX0bf)[8] = (ushort(*)[8])&sBfrag[0];
    ushort* sAfrag = &sBfrag[1536];

    const ushort* w3p = (const ushort*)ws;
    const ushort* w2p = (const ushort*)((const char*)ws + W2P_OFF);
    const ushort* w1p = (const ushort*)((const char*)ws + W1P_OFF);
    const float*  bb1 = (const float*)((const char*)ws + B1_OFF);
    const float*  bb2 = (const float*)((const char*)ws + B2_OFF);
    const float*  bb3 = (const float*)((const char*)ws + B3_OFF);

    const int tid  = threadIdx.x;
    const int lane = tid & 63;
    const int w    = tid >> 6;
    const int g    = lane >> 4;
    const int m15  = lane & 15;
    const int kA   = blockIdx.x * 4;

    int kk0 = kA, kk1 = min(kA+1, K-1), kk2 = min(kA+2, K-1), kk3 = min(kA+3, K-1);
    int nv0 = __builtin_amdgcn_readfirstlane(nvox[kk0]);
    int nv1 = __builtin_amdgcn_readfirstlane(nvox[kk1]);
    int nv2 = __builtin_amdgcn_readfirstlane(nvox[kk2]);
    int nv3 = __builtin_amdgcn_readfirstlane(nvox[kk3]);
    const int lim0=(nv0+15)>>4, lim1=(nv1+15)>>4, lim2=(nv2+15)>>4, lim3=(nv3+15)>>4;
    const int full0=nv0>>4, full1=nv1>>4, full2=nv2>>4, full3=nv3>>4;

    union U8 { bf16x8 v; unsigned u[4]; };

    // ---- B-fragment preloads (L2-hot) ----
    const bf16x8 b1f   = *(const bf16x8*)(w1p + (size_t)lane * 8);
    const bf16x8 w2lof = *(const bf16x8*)(w2p + (size_t)((0 * 4 + w) * 64 + lane) * 8);
    const bf16x8 w2hif = *(const bf16x8*)(w2p + (size_t)((1 * 4 + w) * 64 + lane) * 8);
    bf16x8 b3f[2][4];
    #pragma unroll
    for (int nt = 0; nt < 2; ++nt)
        #pragma unroll
        for (int ks = 0; ks < 4; ++ks)
            b3f[nt][ks] = *(const bf16x8*)(w3p + (size_t)(((w * 2 + nt) * 4 + ks) * 64 + lane) * 8);

    // ---- stage 0: wave w -> voxel w (no barrier after: same-wave LDS RAW) ----
    {
        const int kkw = (w==0)?kk0:(w==1)?kk1:(w==2)?kk2:kk3;
        const int nvw = (w==0)?nv0:(w==1)?nv1:(w==2)?nv2:nv3;
        float4 f = make_float4(0.f, 0.f, 0.f, 0.f);
        if (lane < 48)
            f = *reinterpret_cast<const float4*>(feat + ((size_t)kkw * 48 + lane) * 4);
        float sx = f.x, sy = f.y, sz = f.z;
        #pragma unroll
        for (int d = 1; d < 64; d <<= 1) {
            sx += __shfl_xor(sx, d);
            sy += __shfl_xor(sy, d);
            sz += __shfl_xor(sz, d);
        }
        const float inv = 1.f / (float)nvw;
        if (lane < 48) {
            const float msk = (lane < nvw) ? 1.f : 0.f;
            const float dd = sqrtf(f.x * f.x + f.y * f.y + f.z * f.z);
            U8 a;
            a.u[0] = cvtpk(f.x * msk, f.y * msk);
            a.u[1] = cvtpk(f.z * msk, f.w * msk);
            a.u[2] = cvtpk((f.x - sx * inv) * msk, (f.y - sy * inv) * msk);
            a.u[3] = cvtpk((f.z - sz * inv) * msk, dd * msk);
            *reinterpret_cast<bf16x8*>(&sX0bf[w * 48 + lane][0]) = a.v;
        }
    }

    // ---- layer 1 MFMA: wave w owns voxel w's 3 tiles; agg1 reduced in-wave ----
    {
        const float bb1u = bb1[m15];
        const int limw = (w==0)?lim0:(w==1)?lim1:(w==2)?lim2:lim3;
        const f32x4 ci = {bb1u, bb1u, bb1u, bb1u};
        float pmax = fmaxf(bb1u, 0.f);   // analytic masked-row term (nv<48 always)
        #pragma unroll
        for (int s = 0; s < 3; ++s) {
            if (s < limw) {
                const bf16x8 af = *(const bf16x8*)&sX0bf[w * 48 + s * 16 + m15][0];
                f32x4 acc = __builtin_amdgcn_mfma_f32_16x16x32_bf16(af, b1f, ci, 0, 0, 0);
                float h0 = fmaxf(acc[0], 0.f), h1 = fmaxf(acc[1], 0.f);
                float h2 = fmaxf(acc[2], 0.f), h3 = fmaxf(acc[3], 0.f);
                pmax = fmaxf(pmax, fmaxf(fmaxf(h0, h1), fmaxf(h2, h3)));
                const unsigned p01 = cvtpk(h0, h1), p23 = cvtpk(h2, h3);
                ushort* base = &sAfrag[((w * 3 + s) * 16 + g * 4) * APAD + m15];
                base[0 * APAD] = (ushort)p01;
                base[1 * APAD] = (ushort)(p01 >> 16);
                base[2 * APAD] = (ushort)p23;
                base[3 * APAD] = (ushort)(p23 >> 16);
            }
        }
        pmax = fmaxf(pmax, __shfl_xor(pmax, 16));
        pmax = fmaxf(pmax, __shfl_xor(pmax, 32));
        if (g == 0) sAgg1bf[w][m15] = f2bf(pmax);
    }
    __syncthreads();   // #1: sAfrag + sAgg1bf visible to all waves

    // ---- z2-fold MFMA: A rows cycle voxels (m15&3) -> C reg r = init for voxel r ----
    const int col2 = w * 16 + m15;
    const float bb2c = bb2[col2];
    f32x4 z2acc;
    {
        const bf16x8 az2 = *(const bf16x8*)&sAgg1bf[m15 & 3][(g & 1) * 8];
        f32x4 ci = {bb2c, bb2c, bb2c, bb2c};
        z2acc = __builtin_amdgcn_mfma_f32_16x16x32_bf16(az2, w2hif, ci, 0, 0, 0);
    }

    // ---- layer 2 MFMA: compute ALL 12 tiles into acc2[12] (C-init = bb2+z2) ----
    f32x4 acc2[12];
    {
        #pragma unroll
        for (int vg = 0; vg < 2; ++vg) {
            const f32x4 cP = {z2acc[vg*2],   z2acc[vg*2],   z2acc[vg*2],   z2acc[vg*2]};
            const f32x4 cQ = {z2acc[vg*2+1], z2acc[vg*2+1], z2acc[vg*2+1], z2acc[vg*2+1]};
            #pragma unroll
            for (int j = 0; j < 6; ++j) {
                const int tt = vg * 6 + j;
                const int vox = vg * 2 + j / 3;
                const int mtl = j % 3;
                if (mtl < LIM(vox)) {
                    const bf16x8 af = *(const bf16x8*)&sAfrag[(tt * 16 + m15) * APAD + (g & 1) * 8];
                    acc2[tt] = __builtin_amdgcn_mfma_f32_16x16x32_bf16(af, w2lof, (j < 3) ? cP : cQ, 0, 0, 0);
                }
            }
        }
    }
    __syncthreads();   // #2: sAfrag (and sX0bf) now dead -> sBfrag writes are safe

    // ---- L2 epilogue: h2 = relu(acc2) -> stage frags + agg2 ----
    {
        const int ks = col2 >> 5, gp = (col2 >> 3) & 3, e = col2 & 7;
        float mxv0 = fmaxf(bb2c, 0.f), mxv1 = mxv0, mxv2 = mxv0, mxv3 = mxv0;  // analytic masked-row term
        #pragma unroll
        for (int tt = 0; tt < 12; ++tt) {
            const int vox = tt / 3;
            const int mtl = tt % 3;
            if (mtl < LIM(vox)) {
                float h[4];
                #pragma unroll
                for (int r = 0; r < 4; ++r) h[r] = fmaxf(acc2[tt][r], 0.f);
                const unsigned p01 = cvtpk(h[0], h[1]), p23 = cvtpk(h[2], h[3]);
                ushort* base = &sBfrag[((tt * 2 + ks) * 64 + gp * 16 + g * 4) * 8 + e];
                base[0]  = (ushort)p01;
                base[8]  = (ushort)(p01 >> 16);
                base[16] = (ushort)p23;
                base[24] = (ushort)(p23 >> 16);
                float contrib;
                if (mtl < FULL(vox)) {
                    contrib = fmaxf(fmaxf(h[0], h[1]), fmaxf(h[2], h[3]));
                } else {
                    contrib = 0.f;
                    #pragma unroll
                    for (int r = 0; r < 4; ++r)
                        if (mtl * 16 + g * 4 + r < NV(vox)) contrib = fmaxf(contrib, h[r]);
                }
                if (vox == 0) mxv0 = fmaxf(mxv0, contrib);
                else if (vox == 1) mxv1 = fmaxf(mxv1, contrib);
                else if (vox == 2) mxv2 = fmaxf(mxv2, contrib);
                else mxv3 = fmaxf(mxv3, contrib);
            }
        }
        mxv0 = fmaxf(mxv0, __shfl_xor(mxv0, 16));
        mxv0 = fmaxf(mxv0, __shfl_xor(mxv0, 32));
        mxv1 = fmaxf(mxv1, __shfl_xor(mxv1, 16));
        mxv1 = fmaxf(mxv1, __shfl_xor(mxv1, 32));
        mxv2 = fmaxf(mxv2, __shfl_xor(mxv2, 16));
        mxv2 = fmaxf(mxv2, __shfl_xor(mxv2, 32));
        mxv3 = fmaxf(mxv3, __shfl_xor(mxv3, 16));
        mxv3 = fmaxf(mxv3, __shfl_xor(mxv3, 32));
        if (g == 0) {
            sAgg2bf[0][col2] = f2bf(mxv0);
            sAgg2bf[1][col2] = f2bf(mxv1);
            sAgg2bf[2][col2] = f2bf(mxv2);
            sAgg2bf[3][col2] = f2bf(mxv3);
        }
    }
    __syncthreads();   // #3: sBfrag + sAgg2bf visible

    // ---- z3-fold (C-init = bb3; A rows cycle voxels) -> i3[nt][v] ----
    f32x4 i3[2];
    #pragma unroll
    for (int nt = 0; nt < 2; ++nt) {
        const float bb3c = bb3[(w * 2 + nt) * 16 + m15];
        f32x4 z = {bb3c, bb3c, bb3c, bb3c};
        #pragma unroll
        for (int ks2 = 0; ks2 < 2; ++ks2) {
            const bf16x8 af = *(const bf16x8*)&sAgg2bf[m15 & 3][ks2 * 32 + g * 8];
            z = __builtin_amdgcn_mfma_f32_16x16x32_bf16(af, b3f[nt][2 + ks2], z, 0, 0, 0);
        }
        i3[nt] = z;
    }

    // ---- layer 3 MFMA: 2 passes x two 6-tile halves (C-init = bb3+z3, hoisted splats) ----
    #pragma unroll
    for (int pass = 0; pass < 2; ++pass) {
        const int col = (w * 2 + pass) * 16 + m15;
        #pragma unroll
        for (int vg = 0; vg < 2; ++vg) {
            const f32x4 cP = {i3[pass][vg*2],   i3[pass][vg*2],   i3[pass][vg*2],   i3[pass][vg*2]};
            const f32x4 cQ = {i3[pass][vg*2+1], i3[pass][vg*2+1], i3[pass][vg*2+1], i3[pass][vg*2+1]};
            f32x4 acc3[6];
            __builtin_amdgcn_s_setprio(1);
            #pragma unroll
            for (int j = 0; j < 6; ++j) {
                const int tt = vg * 6 + j;
                const int vox = vg * 2 + j / 3;
                const int mtl = j % 3;
                if (mtl < LIM(vox)) {
                    const bf16x8 af0 = *(const bf16x8*)&sBfrag[((tt * 2 + 0) * 64 + lane) * 8];
                    const bf16x8 af1 = *(const bf16x8*)&sBfrag[((tt * 2 + 1) * 64 + lane) * 8];
                    acc3[j] = __builtin_amdgcn_mfma_f32_16x16x32_bf16(af0, b3f[pass][0], (j < 3) ? cP : cQ, 0, 0, 0);
                    acc3[j] = __builtin_amdgcn_mfma_f32_16x16x32_bf16(af1, b3f[pass][1], acc3[j], 0, 0, 0);
                }
            }
            __builtin_amdgcn_s_setprio(0);
            float mxP = 0.f, mxQ = 0.f;   // relu folded into fmax (mx >= 0)
            #pragma unroll
            for (int j = 0; j < 6; ++j) {
                const int vox = vg * 2 + j / 3;
                const int mtl = j % 3;
                if (mtl < FULL(vox)) {
                    const float t01 = fmaxf(acc3[j][0], acc3[j][1]);
                    const float t23 = fmaxf(acc3[j][2], acc3[j][3]);
                    if (j < 3) mxP = fmaxf(mxP, fmaxf(t01, t23));
                    else       mxQ = fmaxf(mxQ, fmaxf(t01, t23));
                } else if (mtl < LIM(vox)) {
                    #pragma unroll
                    for (int r = 0; r < 4; ++r) {
                        if (mtl * 16 + g * 4 + r < NV(vox)) {
                            if (j < 3) mxP = fmaxf(mxP, acc3[j][r]);
                            else       mxQ = fmaxf(mxQ, acc3[j][r]);
                        }
                    }
                }
            }
            mxP = fmaxf(mxP, __shfl_xor(mxP, 16));
            mxP = fmaxf(mxP, __shfl_xor(mxP, 32));
            mxQ = fmaxf(mxQ, __shfl_xor(mxQ, 16));
            mxQ = fmaxf(mxQ, __shfl_xor(mxQ, 32));
            if (g == (vg * 2 + 0) && (kA + vg * 2 + 0) < K) out[(size_t)(kA + vg * 2 + 0) * 128 + col] = mxP;
            if (g == (vg * 2 + 1) && (kA + vg * 2 + 1) < K) out[(size_t)(kA + vg * 2 + 1) * 128 + col] = mxQ;
        }
    }
}

extern "C" void kernel_launch(void* const* d_in, const int* in_sizes, int n_in,
                              void* d_out, int out_size, void* d_ws, size_t ws_size,
                              hipStream_t stream) {
    const float* feat = (const float*)d_in[0];
    const int*   nvx  = (const int*)d_in[1];
    const float* w1 = (const float*)d_in[3];
    const float* b1 = (const float*)d_in[4];
    const float* g1 = (const float*)d_in[5];
    const float* be1= (const float*)d_in[6];
    const float* m1 = (const float*)d_in[7];
    const float* v1 = (const float*)d_in[8];
    const float* w2 = (const float*)d_in[9];
    const float* b2 = (const float*)d_in[10];
    const float* g2 = (const float*)d_in[11];
    const float* be2= (const float*)d_in[12];
    const float* m2 = (const float*)d_in[13];
    const float* v2 = (const float*)d_in[14];
    const float* w3 = (const float*)d_in[15];
    const float* b3 = (const float*)d_in[16];
    const float* g3 = (const float*)d_in[17];
    const float* be3= (const float*)d_in[18];
    const float* m3 = (const float*)d_in[19];
    const float* v3 = (const float*)d_in[20];
    float* out = (float*)d_out;

    const int K = in_sizes[1];

    vfe_prep<<<84, 256, 0, stream>>>(w1,b1,g1,be1,m1,v1, w2,b2,g2,be2,m2,v2,
                                     w3,b3,g3,be3,m3,v3, d_ws);
    vfe_fused<<<(K + 3) / 4, 256, 0, stream>>>(feat, nvx, d_ws, out, K);
}

// Round 18
// 62.690 us; speedup vs baseline: 1.3304x; 1.3304x over previous
//
#include <hip/hip_runtime.h>

constexpr float EPS = 1e-5f;

typedef __attribute__((ext_vector_type(8))) short bf16x8;
typedef __attribute__((ext_vector_type(4))) float f32x4;

// d_ws layout (bytes):
//   0      : w3p[8nt][4ks][64][8]  bf16, BN-folded. ks 0,1 = h2 rows (k<64); ks 2,3 = agg rows (k>=64)
//   32768  : w2p[2sel][4nt][64][8] bf16, BN-folded. sel0 = w2 rows 0-15 (h1), sel1 = rows 16-31 (agg); k-slots>=16 ZERO
//   40960  : w1p[64][8]            bf16, BN-folded, zeros for k>=8
//   41984  : bb1 f32[16] ; 42048: bb2 f32[64] ; 42304: bb3 f32[128]
#define W2P_OFF 32768
#define W1P_OFF 40960
#define B1_OFF  41984
#define B2_OFF  42048
#define B3_OFF  42304

#define APAD 16

__device__ __forceinline__ ushort f2bf(float x) {
    union { float f; unsigned u; } a; a.f = x;
    unsigned r = a.u + 0x7fffu + ((a.u >> 16) & 1u);   // RTNE (finite inputs only)
    return (ushort)(r >> 16);
}

__device__ __forceinline__ unsigned cvtpk(float lo, float hi) {
    unsigned r;
    asm("v_cvt_pk_bf16_f32 %0, %1, %2" : "=v"(r) : "v"(lo), "v"(hi));
    return r;
}

__global__ void vfe_prep(
    const float* __restrict__ w1, const float* __restrict__ b1,
    const float* __restrict__ g1, const float* __restrict__ be1,
    const float* __restrict__ m1, const float* __restrict__ v1,
    const float* __restrict__ w2, const float* __restrict__ b2,
    const float* __restrict__ g2, const float* __restrict__ be2,
    const float* __restrict__ m2, const float* __restrict__ v2,
    const float* __restrict__ w3, const float* __restrict__ b3,
    const float* __restrict__ g3, const float* __restrict__ be3,
    const float* __restrict__ m3, const float* __restrict__ v3,
    void* __restrict__ ws)
{
    ushort* w3p = (ushort*)ws;
    ushort* w2p = (ushort*)((char*)ws + W2P_OFF);
    ushort* w1p = (ushort*)((char*)ws + W1P_OFF);
    float*  bb1 = (float*)((char*)ws + B1_OFF);
    float*  bb2 = (float*)((char*)ws + B2_OFF);
    float*  bb3 = (float*)((char*)ws + B3_OFF);

    const int i = blockIdx.x * 256 + threadIdx.x;
    if (i < 16384) {                       // w3p: ((nt*4+ks)*64 + l)*8 + e
        const int e = i & 7, l = (i >> 3) & 63, rest = i >> 9;
        const int ks = rest & 3, nt = rest >> 2, g = l >> 4;
        const int k = ks * 32 + g * 8 + e;
        const int n = nt * 16 + (l & 15);
        const float s = g3[n] * rsqrtf(v3[n] + EPS);
        w3p[i] = f2bf(w3[k * 128 + n] * s);
    } else if (i < 20480) {                // w2p: ((sel*4+nt)*64 + l)*8 + e ; zeros k>=16
        const int j = i - 16384;
        const int e = j & 7, l = (j >> 3) & 63, rest = j >> 9;
        const int nt = rest & 3, sel = rest >> 2;
        const int klog = (l >> 4) * 8 + e;             // 0..31, real only <16
        const int n = nt * 16 + (l & 15);
        const float s = g2[n] * rsqrtf(v2[n] + EPS);
        w2p[j] = (klog < 16) ? f2bf(w2[(sel * 16 + klog) * 64 + n] * s) : (ushort)0;
    } else if (i < 20992) {                // w1p: l*8 + e, zeros for k>=8
        const int j = i - 20480;
        const int e = j & 7, l = j >> 3;
        const int klog = (l >> 4) * 8 + e;
        const int u = l & 15;
        const float s = g1[u] * rsqrtf(v1[u] + EPS);
        w1p[j] = (klog < 8) ? f2bf(w1[klog * 16 + u] * s) : (ushort)0;
    } else if (i < 21200) {
        const int j = i - 20992;
        if (j < 16) {
            const int u = j;
            bb1[u] = (b1[u] - m1[u]) * (g1[u] * rsqrtf(v1[u] + EPS)) + be1[u];
        } else if (j < 80) {
            const int u = j - 16;
            bb2[u] = (b2[u] - m2[u]) * (g2[u] * rsqrtf(v2[u] + EPS)) + be2[u];
        } else {
            const int u = j - 80;
            bb3[u] = (b3[u] - m3[u]) * (g3[u] * rsqrtf(v3[u] + EPS)) + be3[u];
        }
    }
}

#define NV(v)   ((v)==0?nv0:(v)==1?nv1:(v)==2?nv2:nv3)
#define LIM(v)  ((v)==0?lim0:(v)==1?lim1:(v)==2?lim2:lim3)
#define FULL(v) ((v)==0?full0:(v)==1?full1:(v)==2?full2:full3)

// 4 voxels per block. R16 structure; R18 = sAfrag unioned into sBfrag TAIL
// (bytes 18432..24575) with ordering: vg0-epilogue writes tiles 0-5 (disjoint),
// barrier only between vg1-compute (last sAfrag read) and vg1-epilogue.
// acc2[6] max live across barriers -> no spill. LDS 25,216 B -> 6 blocks/CU.
__global__ __launch_bounds__(256, 6) void vfe_fused(
    const float* __restrict__ feat,
    const int* __restrict__ nvox,
    const void* __restrict__ ws,
    float* __restrict__ out,
    int K)
{
    __shared__ __align__(16) ushort sBfrag[12 * 2 * 64 * 8]; // 24,576 B
    __shared__ __align__(16) ushort sAgg1bf[4][16];          //    128 B
    __shared__ __align__(16) ushort sAgg2bf[4][64];          //    512 B

    // Unions into sBfrag (lifetimes + placement audited):
    //   sX0bf : bytes 0..3071      (stage0 -> L1, same-wave; dead before any sBfrag write)
    //   sAfrag: bytes 18432..24575 (L1 -> L2-compute; clobbered only by vg1-epilogue AFTER barrier #2)
    ushort (*sX0bf)[8] = (ushort(*)[8])&sBfrag[0];
    ushort* sAfrag = &sBfrag[9216];

    const ushort* w3p = (const ushort*)ws;
    const ushort* w2p = (const ushort*)((const char*)ws + W2P_OFF);
    const ushort* w1p = (const ushort*)((const char*)ws + W1P_OFF);
    const float*  bb1 = (const float*)((const char*)ws + B1_OFF);
    const float*  bb2 = (const float*)((const char*)ws + B2_OFF);
    const float*  bb3 = (const float*)((const char*)ws + B3_OFF);

    const int tid  = threadIdx.x;
    const int lane = tid & 63;
    const int w    = tid >> 6;
    const int g    = lane >> 4;
    const int m15  = lane & 15;
    const int kA   = blockIdx.x * 4;

    int kk0 = kA, kk1 = min(kA+1, K-1), kk2 = min(kA+2, K-1), kk3 = min(kA+3, K-1);
    int nv0 = __builtin_amdgcn_readfirstlane(nvox[kk0]);
    int nv1 = __builtin_amdgcn_readfirstlane(nvox[kk1]);
    int nv2 = __builtin_amdgcn_readfirstlane(nvox[kk2]);
    int nv3 = __builtin_amdgcn_readfirstlane(nvox[kk3]);
    const int lim0=(nv0+15)>>4, lim1=(nv1+15)>>4, lim2=(nv2+15)>>4, lim3=(nv3+15)>>4;
    const int full0=nv0>>4, full1=nv1>>4, full2=nv2>>4, full3=nv3>>4;

    union U8 { bf16x8 v; unsigned u[4]; };

    // ---- stage 0: wave w -> voxel w (no barrier after: same-wave LDS RAW) ----
    {
        const int kkw = (w==0)?kk0:(w==1)?kk1:(w==2)?kk2:kk3;
        const int nvw = (w==0)?nv0:(w==1)?nv1:(w==2)?nv2:nv3;
        float4 f = make_float4(0.f, 0.f, 0.f, 0.f);
        if (lane < 48)
            f = *reinterpret_cast<const float4*>(feat + ((size_t)kkw * 48 + lane) * 4);
        float sx = f.x, sy = f.y, sz = f.z;
        #pragma unroll
        for (int d = 1; d < 64; d <<= 1) {
            sx += __shfl_xor(sx, d);
            sy += __shfl_xor(sy, d);
            sz += __shfl_xor(sz, d);
        }
        const float inv = 1.f / (float)nvw;
        if (lane < 48) {
            const float msk = (lane < nvw) ? 1.f : 0.f;
            const float dd = sqrtf(f.x * f.x + f.y * f.y + f.z * f.z);
            U8 a;
            a.u[0] = cvtpk(f.x * msk, f.y * msk);
            a.u[1] = cvtpk(f.z * msk, f.w * msk);
            a.u[2] = cvtpk((f.x - sx * inv) * msk, (f.y - sy * inv) * msk);
            a.u[3] = cvtpk((f.z - sz * inv) * msk, dd * msk);
            *reinterpret_cast<bf16x8*>(&sX0bf[w * 48 + lane][0]) = a.v;
        }
    }

    // ---- layer 1 MFMA (b1f phase-local): wave w owns voxel w's 3 tiles ----
    {
        const bf16x8 b1f = *(const bf16x8*)(w1p + (size_t)lane * 8);
        const float bb1u = bb1[m15];
        const int limw = (w==0)?lim0:(w==1)?lim1:(w==2)?lim2:lim3;
        const f32x4 ci = {bb1u, bb1u, bb1u, bb1u};
        float pmax = fmaxf(bb1u, 0.f);   // analytic masked-row term (nv<48 always)
        #pragma unroll
        for (int s = 0; s < 3; ++s) {
            if (s < limw) {
                const bf16x8 af = *(const bf16x8*)&sX0bf[w * 48 + s * 16 + m15][0];
                f32x4 acc = __builtin_amdgcn_mfma_f32_16x16x32_bf16(af, b1f, ci, 0, 0, 0);
                float h0 = fmaxf(acc[0], 0.f), h1 = fmaxf(acc[1], 0.f);
                float h2 = fmaxf(acc[2], 0.f), h3 = fmaxf(acc[3], 0.f);
                pmax = fmaxf(pmax, fmaxf(fmaxf(h0, h1), fmaxf(h2, h3)));
                const unsigned p01 = cvtpk(h0, h1), p23 = cvtpk(h2, h3);
                ushort* base = &sAfrag[((w * 3 + s) * 16 + g * 4) * APAD + m15];
                base[0 * APAD] = (ushort)p01;
                base[1 * APAD] = (ushort)(p01 >> 16);
                base[2 * APAD] = (ushort)p23;
                base[3 * APAD] = (ushort)(p23 >> 16);
            }
        }
        pmax = fmaxf(pmax, __shfl_xor(pmax, 16));
        pmax = fmaxf(pmax, __shfl_xor(pmax, 32));
        if (g == 0) sAgg1bf[w][m15] = f2bf(pmax);
    }
    __syncthreads();   // #1: sAfrag + sAgg1bf visible

    // ---- z2-fold MFMA (w2hif phase-local): C reg r = init for voxel r ----
    const int col2 = w * 16 + m15;
    const float bb2c = bb2[col2];
    f32x4 z2acc;
    {
        const bf16x8 w2hif = *(const bf16x8*)(w2p + (size_t)((1 * 4 + w) * 64 + lane) * 8);
        const bf16x8 az2 = *(const bf16x8*)&sAgg1bf[m15 & 3][(g & 1) * 8];
        f32x4 ci = {bb2c, bb2c, bb2c, bb2c};
        z2acc = __builtin_amdgcn_mfma_f32_16x16x32_bf16(az2, w2hif, ci, 0, 0, 0);
    }

    // ---- layer 2: vg0 compute -> vg0 epilogue -> vg1 compute -> BARRIER -> vg1 epilogue ----
    {
        const bf16x8 w2lof = *(const bf16x8*)(w2p + (size_t)((0 * 4 + w) * 64 + lane) * 8);
        const int ks = col2 >> 5, gp = (col2 >> 3) & 3, e = col2 & 7;
        f32x4 acc2[6];

        #pragma unroll
        for (int vg = 0; vg < 2; ++vg) {
            const f32x4 cP = {z2acc[vg*2],   z2acc[vg*2],   z2acc[vg*2],   z2acc[vg*2]};
            const f32x4 cQ = {z2acc[vg*2+1], z2acc[vg*2+1], z2acc[vg*2+1], z2acc[vg*2+1]};
            // compute 6 tiles (reads sAfrag @ bytes 18432+)
            #pragma unroll
            for (int j = 0; j < 6; ++j) {
                const int tt = vg * 6 + j;
                const int vox = vg * 2 + j / 3;
                const int mtl = j % 3;
                if (mtl < LIM(vox)) {
                    const bf16x8 af = *(const bf16x8*)&sAfrag[(tt * 16 + m15) * APAD + (g & 1) * 8];
                    acc2[j] = __builtin_amdgcn_mfma_f32_16x16x32_bf16(af, w2lof, (j < 3) ? cP : cQ, 0, 0, 0);
                }
            }
            // vg1 writes overlap sAfrag -> wait until every wave finished its last sAfrag read
            if (vg == 1) __syncthreads();   // #2
            // epilogue: vg0 writes tiles 0-5 (bytes 0..12287, disjoint from sAfrag);
            //           vg1 writes tiles 6-11 (sAfrag region, now dead)
            float mxP = fmaxf(bb2c, 0.f);
            float mxQ = fmaxf(bb2c, 0.f);
            #pragma unroll
            for (int j = 0; j < 6; ++j) {
                const int tt = vg * 6 + j;
                const int vox = vg * 2 + j / 3;
                const int mtl = j % 3;
                if (mtl < LIM(vox)) {
                    float h[4];
                    #pragma unroll
                    for (int r = 0; r < 4; ++r) h[r] = fmaxf(acc2[j][r], 0.f);
                    const unsigned p01 = cvtpk(h[0], h[1]), p23 = cvtpk(h[2], h[3]);
                    ushort* base = &sBfrag[((tt * 2 + ks) * 64 + gp * 16 + g * 4) * 8 + e];
                    base[0]  = (ushort)p01;
                    base[8]  = (ushort)(p01 >> 16);
                    base[16] = (ushort)p23;
                    base[24] = (ushort)(p23 >> 16);
                    if (mtl < FULL(vox)) {
                        const float t01 = fmaxf(h[0], h[1]), t23 = fmaxf(h[2], h[3]);
                        if (j < 3) mxP = fmaxf(mxP, fmaxf(t01, t23));
                        else       mxQ = fmaxf(mxQ, fmaxf(t01, t23));
                    } else {
                        #pragma unroll
                        for (int r = 0; r < 4; ++r) {
                            if (mtl * 16 + g * 4 + r < NV(vox)) {
                                if (j < 3) mxP = fmaxf(mxP, h[r]);
                                else       mxQ = fmaxf(mxQ, h[r]);
                            }
                        }
                    }
                }
            }
            mxP = fmaxf(mxP, __shfl_xor(mxP, 16));
            mxP = fmaxf(mxP, __shfl_xor(mxP, 32));
            mxQ = fmaxf(mxQ, __shfl_xor(mxQ, 16));
            mxQ = fmaxf(mxQ, __shfl_xor(mxQ, 32));
            if (g == 0) {
                sAgg2bf[vg * 2 + 0][col2] = f2bf(mxP);
                sAgg2bf[vg * 2 + 1][col2] = f2bf(mxQ);
            }
        }
    }
    __syncthreads();   // #3: sBfrag + sAgg2bf visible

    // ---- z3-fold (b3h phase-local, dead after) ----
    f32x4 i3[2];
    {
        bf16x8 b3h[2][2];
        #pragma unroll
        for (int nt = 0; nt < 2; ++nt)
            #pragma unroll
            for (int ks2 = 0; ks2 < 2; ++ks2)
                b3h[nt][ks2] = *(const bf16x8*)(w3p + (size_t)(((w * 2 + nt) * 4 + 2 + ks2) * 64 + lane) * 8);
        #pragma unroll
        for (int nt = 0; nt < 2; ++nt) {
            const float bb3c = bb3[(w * 2 + nt) * 16 + m15];
            f32x4 z = {bb3c, bb3c, bb3c, bb3c};
            #pragma unroll
            for (int ks2 = 0; ks2 < 2; ++ks2) {
                const bf16x8 af = *(const bf16x8*)&sAgg2bf[m15 & 3][ks2 * 32 + g * 8];
                z = __builtin_amdgcn_mfma_f32_16x16x32_bf16(af, b3h[nt][ks2], z, 0, 0, 0);
            }
            i3[nt] = z;
        }
    }

    // ---- layer 3 MFMA: 2 passes x two 6-tile halves (b3l per-pass) ----
    #pragma unroll
    for (int pass = 0; pass < 2; ++pass) {
        const int col = (w * 2 + pass) * 16 + m15;
        bf16x8 b3l[2];
        #pragma unroll
        for (int ks2 = 0; ks2 < 2; ++ks2)
            b3l[ks2] = *(const bf16x8*)(w3p + (size_t)(((w * 2 + pass) * 4 + ks2) * 64 + lane) * 8);
        #pragma unroll
        for (int vg = 0; vg < 2; ++vg) {
            const f32x4 cP = {i3[pass][vg*2],   i3[pass][vg*2],   i3[pass][vg*2],   i3[pass][vg*2]};
            const f32x4 cQ = {i3[pass][vg*2+1], i3[pass][vg*2+1], i3[pass][vg*2+1], i3[pass][vg*2+1]};
            f32x4 acc3[6];
            __builtin_amdgcn_s_setprio(1);
            #pragma unroll
            for (int j = 0; j < 6; ++j) {
                const int tt = vg * 6 + j;
                const int vox = vg * 2 + j / 3;
                const int mtl = j % 3;
                if (mtl < LIM(vox)) {
                    const bf16x8 af0 = *(const bf16x8*)&sBfrag[((tt * 2 + 0) * 64 + lane) * 8];
                    const bf16x8 af1 = *(const bf16x8*)&sBfrag[((tt * 2 + 1) * 64 + lane) * 8];
                    acc3[j] = __builtin_amdgcn_mfma_f32_16x16x32_bf16(af0, b3l[0], (j < 3) ? cP : cQ, 0, 0, 0);
                    acc3[j] = __builtin_amdgcn_mfma_f32_16x16x32_bf16(af1, b3l[1], acc3[j], 0, 0, 0);
                }
            }
            __builtin_amdgcn_s_setprio(0);
            float mxP = 0.f, mxQ = 0.f;   // relu folded into fmax (mx >= 0)
            #pragma unroll
            for (int j = 0; j < 6; ++j) {
                const int vox = vg * 2 + j / 3;
                const int mtl = j % 3;
                if (mtl < FULL(vox)) {
                    const float t01 = fmaxf(acc3[j][0], acc3[j][1]);
                    const float t23 = fmaxf(acc3[j][2], acc3[j][3]);
                    if (j < 3) mxP = fmaxf(mxP, fmaxf(t01, t23));
                    else       mxQ = fmaxf(mxQ, fmaxf(t01, t23));
                } else if (mtl < LIM(vox)) {
                    #pragma unroll
                    for (int r = 0; r < 4; ++r) {
                        if (mtl * 16 + g * 4 + r < NV(vox)) {
                            if (j < 3) mxP = fmaxf(mxP, acc3[j][r]);
                            else       mxQ = fmaxf(mxQ, acc3[j][r]);
                        }
                    }
                }
            }
            mxP = fmaxf(mxP, __shfl_xor(mxP, 16));
            mxP = fmaxf(mxP, __shfl_xor(mxP, 32));
            mxQ = fmaxf(mxQ, __shfl_xor(mxQ, 16));
            mxQ = fmaxf(mxQ, __shfl_xor(mxQ, 32));
            if (g == (vg * 2 + 0) && (kA + vg * 2 + 0) < K) out[(size_t)(kA + vg * 2 + 0) * 128 + col] = mxP;
            if (g == (vg * 2 + 1) && (kA + vg * 2 + 1) < K) out[(size_t)(kA + vg * 2 + 1) * 128 + col] = mxQ;
        }
    }
}

extern "C" void kernel_launch(void* const* d_in, const int* in_sizes, int n_in,
                              void* d_out, int out_size, void* d_ws, size_t ws_size,
                              hipStream_t stream) {
    const float* feat = (const float*)d_in[0];
    const int*   nvx  = (const int*)d_in[1];
    const float* w1 = (const float*)d_in[3];
    const float* b1 = (const float*)d_in[4];
    const float* g1 = (const float*)d_in[5];
    const float* be1= (const float*)d_in[6];
    const float* m1 = (const float*)d_in[7];
    const float* v1 = (const float*)d_in[8];
    const float* w2 = (const float*)d_in[9];
    const float* b2 = (const float*)d_in[10];
    const float* g2 = (const float*)d_in[11];
    const float* be2= (const float*)d_in[12];
    const float* m2 = (const float*)d_in[13];
    const float* v2 = (const float*)d_in[14];
    const float* w3 = (const float*)d_in[15];
    const float* b3 = (const float*)d_in[16];
    const float* g3 = (const float*)d_in[17];
    const float* be3= (const float*)d_in[18];
    const float* m3 = (const float*)d_in[19];
    const float* v3 = (const float*)d_in[20];
    float* out = (float*)d_out;

    const int K = in_sizes[1];

    vfe_prep<<<84, 256, 0, stream>>>(w1,b1,g1,be1,m1,v1, w2,b2,g2,be2,m2,v2,
                                     w3,b3,g3,be3,m3,v3, d_ws);
    vfe_fused<<<(K + 3) / 4, 256, 0, stream>>>(feat, nvx, d_ws, out, K);
}